// Round 17
// baseline (83.745 us; speedup 1.0000x reference)
//
#include <hip/hip_runtime.h>

typedef __attribute__((ext_vector_type(8))) short short8;
typedef __attribute__((ext_vector_type(4))) float f32x4;
typedef __attribute__((ext_vector_type(16))) float f32x16;

#define HF 256
#define WF 256

typedef const __attribute__((address_space(1))) void gbl_void;
typedef __attribute__((address_space(3))) void lds_void;

__device__ __forceinline__ ushort f2bf(float f) {
    uint u = __builtin_bit_cast(uint, f);
    u = (u + 0x7FFFu + ((u >> 16) & 1u)) >> 16;
    return (ushort)u;
}
__device__ __forceinline__ uint pack2(float a, float b) {
    return (uint)f2bf(a) | ((uint)f2bf(b) << 16);
}
__device__ __forceinline__ float prelu(float v, float al) { return v >= 0.f ? v : al * v; }

// ---------------------------------------------------------------------------
// Fused weight prep (unchanged)
// ---------------------------------------------------------------------------
__global__ __launch_bounds__(256) void k_wprep(const float* __restrict__ w1,
                                               const float* __restrict__ w2,
                                               const float* __restrict__ wup,
                                               ushort* __restrict__ wT1,
                                               ushort* __restrict__ wT2,
                                               ushort* __restrict__ wupT,
                                               uint4* __restrict__ zeroBuf) {
    int idx = blockIdx.x * 256 + threadIdx.x;
    if (blockIdx.x == 0 && threadIdx.x < 16)
        zeroBuf[threadIdx.x] = make_uint4(0u, 0u, 0u, 0u);
    if (idx < 36864) {
        int tap = idx >> 12;
        int oc  = idx & 4095;
        int src = oc * 9 + tap;
        wT1[idx] = f2bf(w1[src]);
        wT2[idx] = f2bf(w2[src]);
    }
    if (idx < 32768) {
        int out = idx >> 7;
        int c   = idx & 127;
        int k   = out >> 6;
        int o   = out & 63;
        wupT[idx] = f2bf(wup[c * 256 + o * 4 + k]);
    }
}

// ---------------------------------------------------------------------------
// ConvTranspose2d k=2 s=2 for b=2,3 via bf16 MFMA (unchanged — known good)
// ---------------------------------------------------------------------------
__global__ __launch_bounds__(512) void k_upsample_mfma(const float* __restrict__ x1,
                                                       const ushort* __restrict__ wupT,
                                                       const float* __restrict__ bup,
                                                       ushort* __restrict__ upB) {
    __shared__ __align__(16) char lds[81920];

    const int t   = threadIdx.x;
    const int l   = t & 63;
    const int l15 = l & 15;
    const int l4  = l >> 4;
    const int w   = t >> 6;
    const int pg  = w & 3;
    const int oh  = w >> 2;
    const int i   = blockIdx.x >> 1;
    const int j0  = (blockIdx.x & 1) * 64;
    const int z   = blockIdx.y;
    const int gb  = 2 + z;

    {
        const int j  = t & 63;
        const int cg = t >> 6;
        const size_t base = ((size_t)gb * 128) * 16384 + (size_t)i * 128 + j0 + j;
        float xv[16];
#pragma unroll
        for (int r = 0; r < 2; ++r)
#pragma unroll
            for (int cc = 0; cc < 8; ++cc)
                xv[r * 8 + cc] = x1[base + (size_t)(cg * 16 + r * 8 + cc) * 16384];
#pragma unroll
        for (int r = 0; r < 2; ++r) {
            short8 pk;
#pragma unroll
            for (int cc = 0; cc < 8; ++cc) pk[cc] = (short)f2bf(xv[r * 8 + cc]);
            int ad = (j * 256 + (cg * 16 + r * 8) * 2) ^ ((j & 15) << 4);
            *(short8*)(lds + ad) = pk;
        }
    }
    {
        const uint4* src = (const uint4*)wupT;
#pragma unroll
        for (int rep = 0; rep < 8; ++rep) {
            int q   = rep * 512 + t;
            int out = q >> 4, c16 = q & 15;
            int ad  = 16384 + ((out * 256 + c16 * 16) ^ ((out & 15) << 4));
            *(uint4*)(lds + ad) = src[q];
        }
    }
    float bvv[4];
#pragma unroll
    for (int ob = 0; ob < 4; ++ob) bvv[ob] = bup[ob * 16 + l15];
    __syncthreads();

    f32x4 acc[2][4];
#pragma unroll
    for (int kk = 0; kk < 2; ++kk)
#pragma unroll
        for (int ob = 0; ob < 4; ++ob) acc[kk][ob] = (f32x4){0.f, 0.f, 0.f, 0.f};

#pragma unroll
    for (int ks = 0; ks < 4; ++ks) {
        const int cb = ks * 64 + (l4 << 4);
        const int rowA = pg * 16 + l15;
        short8 xfr = *(const short8*)(lds + ((rowA * 256 + cb) ^ ((rowA & 15) << 4)));
#pragma unroll
        for (int kk = 0; kk < 2; ++kk)
#pragma unroll
            for (int ob = 0; ob < 4; ++ob) {
                int out = (oh * 2 + kk) * 64 + ob * 16 + l15;
                short8 wfr = *(const short8*)(lds + 16384 +
                              ((out * 256 + cb) ^ ((out & 15) << 4)));
                acc[kk][ob] = __builtin_amdgcn_mfma_f32_16x16x32_bf16(xfr, wfr, acc[kk][ob], 0, 0, 0);
            }
    }
    __syncthreads();

    ushort* OUT = (ushort*)lds;
#pragma unroll
    for (int kk = 0; kk < 2; ++kk) {
        const int k = oh * 2 + kk, p = k >> 1, q = k & 1;
#pragma unroll
        for (int ob = 0; ob < 4; ++ob) {
            const int o = ob * 16 + l15;
#pragma unroll
            for (int r = 0; r < 4; ++r) {
                int jl = pg * 16 + l4 * 4 + r;
                int x  = 2 * jl + q;
                OUT[(p * 128 + x) * 64 + o] = f2bf(acc[kk][ob][r] + bvv[ob]);
            }
        }
    }
    __syncthreads();

#pragma unroll
    for (int rep = 0; rep < 4; ++rep) {
        int idx = rep * 512 + t;
        int p   = idx >> 10;
        int y   = 2 * i + p;
        uint4 v = *(const uint4*)(lds + idx * 16);
        size_t g = (size_t)(z * HF + y) * 2048 + (size_t)j0 * 16 + (idx & 1023);
        ((uint4*)upB)[g] = v;
    }
}

// ---------------------------------------------------------------------------
// k_conv v13: R11/R14 structure UNCHANGED (1024 thr / 16 waves, tile 32x16,
// all weights + input in LDS, 1 barrier, async gload_lds staging) with the
// K-loop moved to mfma_f32_32x32x16_bf16: wave = 1 row x 64 couts via
// 2 MFMAs per 16-ch k-step (W = 2x 32-cout frags, X = 1x 32-pos frag).
// Per wave: 72 MFMAs (was 144), 108->108 reads but 8 fewer per tap.
// C/D layout per m74/m101: col=lane&31, row=(reg&3)+8*(reg>>2)+4*(lane>>5).
// ---------------------------------------------------------------------------
template<int IN_MODE, int OUT_NHWC>
__global__ __launch_bounds__(1024, 1) void k_conv(const float* __restrict__ x2,
                                                  const ushort* __restrict__ upB,
                                                  const ushort* __restrict__ inB,
                                                  const ushort* __restrict__ wT,
                                                  const float* __restrict__ bias,
                                                  const float* __restrict__ alpha,
                                                  const uint4* __restrict__ zeroBuf,
                                                  ushort* __restrict__ outB,
                                                  float* __restrict__ outF) {
    __shared__ __align__(16) ushort inL[5120 * 8];       // 80 KB (4896 used + pad)
    __shared__ __align__(16) ushort wL[9 * 64 * 64];     // 72 KB [tap][o][c], swz on o

    const int t   = threadIdx.x;
    const int wv  = t >> 6;          // wave id -> output row (0..15)
    const int l   = t & 63;
    const int l31 = l & 31;
    const int hi  = l >> 5;          // k-half select
    const int x0  = (blockIdx.x & 7) * 32;
    const int y0  = (blockIdx.x >> 3) * 16;
    const int b   = blockIdx.y;

    // ---- stage ALL weights: linear dest, pre-swizzled source (4608 uint4)
    {
        const char* wTb = (const char*)wT;
#pragma unroll
        for (int rep = 0; rep < 4; ++rep) {
            int d   = rep * 1024 + t;
            int tap = d >> 9;
            int dp  = d & 511;
            int s   = (tap << 9) + (dp ^ ((dp >> 3) & 7));
            __builtin_amdgcn_global_load_lds(
                (gbl_void*)(wTb + (size_t)s * 16),
                (lds_void*)((char*)wL + (size_t)((rep << 10) + (wv << 6)) * 16),
                16, 0, 0);
        }
        if (wv < 8) {                              // wave-uniform tail: 4096..4607
            int d   = 4096 + (wv << 6) + l;
            int tap = d >> 9;
            int dp  = d & 511;
            int s   = (tap << 9) + (dp ^ ((dp >> 3) & 7));
            __builtin_amdgcn_global_load_lds(
                (gbl_void*)(wTb + (size_t)s * 16),
                (lds_void*)((char*)wL + (size_t)(4096 + (wv << 6)) * 16),
                16, 0, 0);
        }
    }

    // ---- stage input tile (18 x 34 x 64ch = 4896 uint4, padded to 5120)
    if (IN_MODE == 1 || b >= 2) {
        const ushort* src0 = (IN_MODE == 1) ? inB : upB;
        const int bb = (IN_MODE == 1) ? b : (b - 2);
#pragma unroll
        for (int rep = 0; rep < 5; ++rep) {
            int d  = rep * 1024 + t;                 // 0..5119
            int r  = d / 272;
            int wi = d - r * 272;
            int wq = wi ^ ((wi >> 3) & 7);           // pre-swizzled source element
            int x  = wq >> 3, c8 = wq & 7;
            int gy = y0 - 1 + r;
            int gx = x0 - 1 + x;
            const void* g;
            if (d < 4896 && (unsigned)gy < HF && (unsigned)gx < WF) {
                size_t pos = (size_t)(bb * HF + gy) * WF + gx;
                g = (const void*)(src0 + pos * 64 + c8 * 8);
            } else {
                g = (const void*)zeroBuf;
            }
            __builtin_amdgcn_global_load_lds(
                (gbl_void*)g,
                (lds_void*)((char*)inL + (size_t)((rep << 10) + (wv << 6)) * 16),
                16, 0, 0);
        }
    } else {
        // manual path: x2 f32 NHWC -> bf16, swizzled ds_write
        for (int q = t; q < 18 * 34 * 8; q += 1024) {
            int r   = q / 272;
            int rem = q - r * 272;
            int x   = rem >> 3;
            int c8  = rem & 7;
            int gy = y0 - 1 + r;
            int gx = x0 - 1 + x;
            uint4 v = make_uint4(0u, 0u, 0u, 0u);
            if ((unsigned)gy < HF && (unsigned)gx < WF) {
                size_t pos = (size_t)(b * HF + gy) * WF + gx;
                const float4* s = (const float4*)(x2 + pos * 64 + c8 * 8);
                float4 u0 = s[0], u1 = s[1];
                v = make_uint4(pack2(u0.x, u0.y), pack2(u0.z, u0.w),
                               pack2(u1.x, u1.y), pack2(u1.z, u1.w));
            }
            int ad = (q * 16) ^ ((x & 7) << 4);
            *(uint4*)((char*)inL + ad) = v;
        }
    }
    __syncthreads();

    f32x16 acc[2];   // [cout-half] (conv1) / [cout-half] (conv2)
#pragma unroll
    for (int n = 0; n < 2; ++n)
#pragma unroll
        for (int r = 0; r < 16; ++r) acc[n][r] = 0.f;

    // ---- K-loop: 9 taps x 4 k-steps; per k-step: 2 W-frags + 1 X-frag,
    // 2 MFMAs of 32x32x16 (72 MFMAs/wave total, fully unrolled).
#pragma unroll
    for (int tap = 0; tap < 9; ++tap) {
        const int ky = tap / 3;
        const int kx = tap % 3;
        const char* wPage = (const char*)wL + tap * 8192;
#pragma unroll
        for (int kst = 0; kst < 4; ++kst) {
            const int kb = kst * 32 + (hi << 4);   // byte offset of lane's 8-ch chunk
            short8 wfr[2];
#pragma unroll
            for (int n = 0; n < 2; ++n) {
                int o = n * 32 + l31;
                int ad = (o * 128 + kb) ^ ((o & 7) << 4);
                wfr[n] = *(const short8*)(wPage + ad);
            }
            int ry = wv + ky;
            int xl = l31 + kx;
            int ad = ((ry * 34 + xl) * 128 + kb) ^ ((xl & 7) << 4);
            short8 ifr = *(const short8*)((const char*)inL + ad);
#pragma unroll
            for (int n = 0; n < 2; ++n) {
                if (OUT_NHWC)
                    acc[n] = __builtin_amdgcn_mfma_f32_32x32x16_bf16(
                        wfr[n], ifr, acc[n], 0, 0, 0);   // D: row=cout, col=pos
                else
                    acc[n] = __builtin_amdgcn_mfma_f32_32x32x16_bf16(
                        ifr, wfr[n], acc[n], 0, 0, 0);   // D: row=pos, col=cout
            }
        }
    }

    const float al = alpha[0];
    const int y = y0 + wv;
    if (OUT_NHWC) {
        // lane l = position x0+l31; reg (rq,j): cout = n*32 + rq*8 + hi*4 + j
        const size_t rowbase = ((size_t)(b * HF + y) * WF + x0 + l31) * 64;
#pragma unroll
        for (int n = 0; n < 2; ++n)
#pragma unroll
            for (int rq = 0; rq < 4; ++rq) {
                int cb = n * 32 + rq * 8 + hi * 4;
                float4 bv = *(const float4*)(bias + cb);
                float p0 = prelu(acc[n][rq * 4 + 0] + bv.x, al);
                float p1 = prelu(acc[n][rq * 4 + 1] + bv.y, al);
                float p2 = prelu(acc[n][rq * 4 + 2] + bv.z, al);
                float p3 = prelu(acc[n][rq * 4 + 3] + bv.w, al);
                *(uint2*)(outB + rowbase + cb) = make_uint2(pack2(p0, p1), pack2(p2, p3));
            }
    } else {
        // lane l = cout n*32+l31; reg (rq,j): x = x0 + rq*8 + hi*4 + j
#pragma unroll
        for (int n = 0; n < 2; ++n) {
            int cout = n * 32 + l31;
            float bb = bias[cout];
            float* obase = outF + (((size_t)b * 64 + cout) << 16) + y * WF + x0;
#pragma unroll
            for (int rq = 0; rq < 4; ++rq) {
                float4 st;
                st.x = prelu(acc[n][rq * 4 + 0] + bb, al);
                st.y = prelu(acc[n][rq * 4 + 1] + bb, al);
                st.z = prelu(acc[n][rq * 4 + 2] + bb, al);
                st.w = prelu(acc[n][rq * 4 + 3] + bb, al);
                *(float4*)(obase + rq * 8 + hi * 4) = st;
            }
        }
    }
}

// ---------------------------------------------------------------------------
extern "C" void kernel_launch(void* const* d_in, const int* in_sizes, int n_in,
                              void* d_out, int out_size, void* d_ws, size_t ws_size,
                              hipStream_t stream) {
    const float* x1  = (const float*)d_in[0];
    const float* x2  = (const float*)d_in[1];
    const float* wup = (const float*)d_in[2];
    const float* bup = (const float*)d_in[3];
    const float* w1  = (const float*)d_in[4];
    const float* b1  = (const float*)d_in[5];
    const float* a1  = (const float*)d_in[6];
    const float* w2  = (const float*)d_in[7];
    const float* b2  = (const float*)d_in[8];
    const float* a2  = (const float*)d_in[9];

    char* ws = (char*)d_ws;
    ushort* upB  = (ushort*)ws;                          // 16 MiB (b=2,3 NHWC bf16)
    ushort* hB   = (ushort*)(ws + (size_t)(16 << 20));   // 32 MiB (NHWC bf16)
    ushort* wT1  = (ushort*)(ws + (size_t)(48 << 20));   // 72 KiB
    ushort* wT2  = wT1 + 9 * 64 * 64;                    // 72 KiB
    ushort* wupT = wT2 + 9 * 64 * 64;                    // 64 KiB
    uint4*  zeroBuf = (uint4*)(ws + (size_t)(49 << 20)); // 256 B
    float* out = (float*)d_out;

    k_wprep<<<144, 256, 0, stream>>>(w1, w2, wup, wT1, wT2, wupT, zeroBuf);
    k_upsample_mfma<<<dim3(256, 2), 512, 0, stream>>>(x1, wupT, bup, upB);
    k_conv<0, 1><<<dim3(128, 4), 1024, 0, stream>>>(x2, upB, nullptr, wT1, b1, a1, zeroBuf, hB, nullptr);
    k_conv<1, 0><<<dim3(128, 4), 1024, 0, stream>>>(nullptr, nullptr, hB, wT2, b2, a2, zeroBuf, nullptr, out);
}

// Round 18
// 83.315 us; speedup vs baseline: 1.0052x; 1.0052x over previous
//
#include <hip/hip_runtime.h>

typedef __attribute__((ext_vector_type(8))) short short8;
typedef __attribute__((ext_vector_type(4))) float f32x4;

#define HF 256
#define WF 256

typedef const __attribute__((address_space(1))) void gbl_void;
typedef __attribute__((address_space(3))) void lds_void;

__device__ __forceinline__ ushort f2bf(float f) {
    uint u = __builtin_bit_cast(uint, f);
    u = (u + 0x7FFFu + ((u >> 16) & 1u)) >> 16;
    return (ushort)u;
}
__device__ __forceinline__ uint pack2(float a, float b) {
    return (uint)f2bf(a) | ((uint)f2bf(b) << 16);
}
__device__ __forceinline__ float prelu(float v, float al) { return v >= 0.f ? v : al * v; }

// ---------------------------------------------------------------------------
// Fused weight prep (unchanged)
// ---------------------------------------------------------------------------
__global__ __launch_bounds__(256) void k_wprep(const float* __restrict__ w1,
                                               const float* __restrict__ w2,
                                               const float* __restrict__ wup,
                                               ushort* __restrict__ wT1,
                                               ushort* __restrict__ wT2,
                                               ushort* __restrict__ wupT,
                                               uint4* __restrict__ zeroBuf) {
    int idx = blockIdx.x * 256 + threadIdx.x;
    if (blockIdx.x == 0 && threadIdx.x < 16)
        zeroBuf[threadIdx.x] = make_uint4(0u, 0u, 0u, 0u);
    if (idx < 36864) {
        int tap = idx >> 12;
        int oc  = idx & 4095;
        int src = oc * 9 + tap;
        wT1[idx] = f2bf(w1[src]);
        wT2[idx] = f2bf(w2[src]);
    }
    if (idx < 32768) {
        int out = idx >> 7;
        int c   = idx & 127;
        int k   = out >> 6;
        int o   = out & 63;
        wupT[idx] = f2bf(wup[c * 256 + o * 4 + k]);
    }
}

// ---------------------------------------------------------------------------
// ConvTranspose2d k=2 s=2 for b=2,3 via bf16 MFMA (unchanged — known good)
// ---------------------------------------------------------------------------
__global__ __launch_bounds__(512) void k_upsample_mfma(const float* __restrict__ x1,
                                                       const ushort* __restrict__ wupT,
                                                       const float* __restrict__ bup,
                                                       ushort* __restrict__ upB) {
    __shared__ __align__(16) char lds[81920];

    const int t   = threadIdx.x;
    const int l   = t & 63;
    const int l15 = l & 15;
    const int l4  = l >> 4;
    const int w   = t >> 6;
    const int pg  = w & 3;
    const int oh  = w >> 2;
    const int i   = blockIdx.x >> 1;
    const int j0  = (blockIdx.x & 1) * 64;
    const int z   = blockIdx.y;
    const int gb  = 2 + z;

    {
        const int j  = t & 63;
        const int cg = t >> 6;
        const size_t base = ((size_t)gb * 128) * 16384 + (size_t)i * 128 + j0 + j;
        float xv[16];
#pragma unroll
        for (int r = 0; r < 2; ++r)
#pragma unroll
            for (int cc = 0; cc < 8; ++cc)
                xv[r * 8 + cc] = x1[base + (size_t)(cg * 16 + r * 8 + cc) * 16384];
#pragma unroll
        for (int r = 0; r < 2; ++r) {
            short8 pk;
#pragma unroll
            for (int cc = 0; cc < 8; ++cc) pk[cc] = (short)f2bf(xv[r * 8 + cc]);
            int ad = (j * 256 + (cg * 16 + r * 8) * 2) ^ ((j & 15) << 4);
            *(short8*)(lds + ad) = pk;
        }
    }
    {
        const uint4* src = (const uint4*)wupT;
#pragma unroll
        for (int rep = 0; rep < 8; ++rep) {
            int q   = rep * 512 + t;
            int out = q >> 4, c16 = q & 15;
            int ad  = 16384 + ((out * 256 + c16 * 16) ^ ((out & 15) << 4));
            *(uint4*)(lds + ad) = src[q];
        }
    }
    float bvv[4];
#pragma unroll
    for (int ob = 0; ob < 4; ++ob) bvv[ob] = bup[ob * 16 + l15];
    __syncthreads();

    f32x4 acc[2][4];
#pragma unroll
    for (int kk = 0; kk < 2; ++kk)
#pragma unroll
        for (int ob = 0; ob < 4; ++ob) acc[kk][ob] = (f32x4){0.f, 0.f, 0.f, 0.f};

#pragma unroll
    for (int ks = 0; ks < 4; ++ks) {
        const int cb = ks * 64 + (l4 << 4);
        const int rowA = pg * 16 + l15;
        short8 xfr = *(const short8*)(lds + ((rowA * 256 + cb) ^ ((rowA & 15) << 4)));
#pragma unroll
        for (int kk = 0; kk < 2; ++kk)
#pragma unroll
            for (int ob = 0; ob < 4; ++ob) {
                int out = (oh * 2 + kk) * 64 + ob * 16 + l15;
                short8 wfr = *(const short8*)(lds + 16384 +
                              ((out * 256 + cb) ^ ((out & 15) << 4)));
                acc[kk][ob] = __builtin_amdgcn_mfma_f32_16x16x32_bf16(xfr, wfr, acc[kk][ob], 0, 0, 0);
            }
    }
    __syncthreads();

    ushort* OUT = (ushort*)lds;
#pragma unroll
    for (int kk = 0; kk < 2; ++kk) {
        const int k = oh * 2 + kk, p = k >> 1, q = k & 1;
#pragma unroll
        for (int ob = 0; ob < 4; ++ob) {
            const int o = ob * 16 + l15;
#pragma unroll
            for (int r = 0; r < 4; ++r) {
                int jl = pg * 16 + l4 * 4 + r;
                int x  = 2 * jl + q;
                OUT[(p * 128 + x) * 64 + o] = f2bf(acc[kk][ob][r] + bvv[ob]);
            }
        }
    }
    __syncthreads();

#pragma unroll
    for (int rep = 0; rep < 4; ++rep) {
        int idx = rep * 512 + t;
        int p   = idx >> 10;
        int y   = 2 * i + p;
        uint4 v = *(const uint4*)(lds + idx * 16);
        size_t g = (size_t)(z * HF + y) * 2048 + (size_t)j0 * 16 + (idx & 1023);
        ((uint4*)upB)[g] = v;
    }
}

// ---------------------------------------------------------------------------
// k_conv v14: R14 structure + COALESCED EPILOGUE via LDS restage.
// After the K-loop, inL/wL are dead: acc (+bias+PReLU) is written into an
// LDS overlay in exact output layout (conv1: [16r][32x][64c] bf16, 64 KB;
// conv2: [64c][16r][32x] f32, 128 KB), then copied out in full contiguous
// 128B segments — replacing the 8-16B scattered stores carried since R4.
// ---------------------------------------------------------------------------
template<int IN_MODE, int OUT_NHWC>
__global__ __launch_bounds__(1024, 1) void k_conv(const float* __restrict__ x2,
                                                  const ushort* __restrict__ upB,
                                                  const ushort* __restrict__ inB,
                                                  const ushort* __restrict__ wT,
                                                  const float* __restrict__ bias,
                                                  const float* __restrict__ alpha,
                                                  const uint4* __restrict__ zeroBuf,
                                                  ushort* __restrict__ outB,
                                                  float* __restrict__ outF) {
    __shared__ __align__(16) char ldsAll[155648];
    ushort* inL = (ushort*)ldsAll;               // [0, 81920): input, swz on x
    char*   wLb = ldsAll + 81920;                // [81920, 155648): weights, swz on o

    const int t   = threadIdx.x;
    const int wv  = t >> 6;          // wave id -> output row (0..15)
    const int l   = t & 63;
    const int l15 = l & 15;
    const int l4  = l >> 4;
    const int x0  = (blockIdx.x & 7) * 32;
    const int y0  = (blockIdx.x >> 3) * 16;
    const int b   = blockIdx.y;

    // ---- stage ALL weights: linear dest, pre-swizzled source (4608 uint4)
    {
        const char* wTb = (const char*)wT;
#pragma unroll
        for (int rep = 0; rep < 4; ++rep) {
            int d   = rep * 1024 + t;
            int tap = d >> 9;
            int dp  = d & 511;
            int s   = (tap << 9) + (dp ^ ((dp >> 3) & 7));
            __builtin_amdgcn_global_load_lds(
                (gbl_void*)(wTb + (size_t)s * 16),
                (lds_void*)(wLb + (size_t)((rep << 10) + (wv << 6)) * 16),
                16, 0, 0);
        }
        if (wv < 8) {                              // wave-uniform tail: 4096..4607
            int d   = 4096 + (wv << 6) + l;
            int tap = d >> 9;
            int dp  = d & 511;
            int s   = (tap << 9) + (dp ^ ((dp >> 3) & 7));
            __builtin_amdgcn_global_load_lds(
                (gbl_void*)(wTb + (size_t)s * 16),
                (lds_void*)(wLb + (size_t)(4096 + (wv << 6)) * 16),
                16, 0, 0);
        }
    }

    // ---- stage input tile (18 x 34 x 64ch = 4896 uint4, padded to 5120)
    if (IN_MODE == 1 || b >= 2) {
        const ushort* src0 = (IN_MODE == 1) ? inB : upB;
        const int bb = (IN_MODE == 1) ? b : (b - 2);
#pragma unroll
        for (int rep = 0; rep < 5; ++rep) {
            int d  = rep * 1024 + t;                 // 0..5119
            int r  = d / 272;
            int wi = d - r * 272;
            int wq = wi ^ ((wi >> 3) & 7);           // pre-swizzled source element
            int x  = wq >> 3, c8 = wq & 7;
            int gy = y0 - 1 + r;
            int gx = x0 - 1 + x;
            const void* g;
            if (d < 4896 && (unsigned)gy < HF && (unsigned)gx < WF) {
                size_t pos = (size_t)(bb * HF + gy) * WF + gx;
                g = (const void*)(src0 + pos * 64 + c8 * 8);
            } else {
                g = (const void*)zeroBuf;
            }
            __builtin_amdgcn_global_load_lds(
                (gbl_void*)g,
                (lds_void*)((char*)inL + (size_t)((rep << 10) + (wv << 6)) * 16),
                16, 0, 0);
        }
    } else {
        // manual path: x2 f32 NHWC -> bf16, swizzled ds_write
        for (int q = t; q < 18 * 34 * 8; q += 1024) {
            int r   = q / 272;
            int rem = q - r * 272;
            int x   = rem >> 3;
            int c8  = rem & 7;
            int gy = y0 - 1 + r;
            int gx = x0 - 1 + x;
            uint4 v = make_uint4(0u, 0u, 0u, 0u);
            if ((unsigned)gy < HF && (unsigned)gx < WF) {
                size_t pos = (size_t)(b * HF + gy) * WF + gx;
                const float4* s = (const float4*)(x2 + pos * 64 + c8 * 8);
                float4 u0 = s[0], u1 = s[1];
                v = make_uint4(pack2(u0.x, u0.y), pack2(u0.z, u0.w),
                               pack2(u1.x, u1.y), pack2(u1.z, u1.w));
            }
            int ad = (q * 16) ^ ((x & 7) << 4);
            *(uint4*)((char*)inL + ad) = v;
        }
    }
    __syncthreads();

    f32x4 acc[2][4];   // [m][nf]
#pragma unroll
    for (int m = 0; m < 2; ++m)
#pragma unroll
        for (int nf = 0; nf < 4; ++nf) acc[m][nf] = (f32x4){0.f, 0.f, 0.f, 0.f};

    // ---- K-loop: fully unrolled, pure LDS + MFMA (R14, known good)
#pragma unroll
    for (int tap = 0; tap < 9; ++tap) {
        const int ky = tap / 3;
        const int kx = tap % 3;
        const char* wPage = wLb + tap * 8192;
#pragma unroll
        for (int ks = 0; ks < 2; ++ks) {
            short8 wfr[4];
#pragma unroll
            for (int nf = 0; nf < 4; ++nf) {
                int o = nf * 16 + l15;
                int ad = (o * 128 + ks * 64 + (l4 << 4)) ^ ((o & 7) << 4);
                wfr[nf] = *(const short8*)(wPage + ad);
            }
#pragma unroll
            for (int m = 0; m < 2; ++m) {
                int ry = wv + ky;
                int xl = m * 16 + l15 + kx;
                int ad = ((ry * 34 + xl) * 128 + ks * 64 + (l4 << 4)) ^ ((xl & 7) << 4);
                short8 ifr = *(const short8*)((const char*)inL + ad);
#pragma unroll
                for (int nf = 0; nf < 4; ++nf) {
                    if (OUT_NHWC)
                        acc[m][nf] = __builtin_amdgcn_mfma_f32_16x16x32_bf16(
                            wfr[nf], ifr, acc[m][nf], 0, 0, 0);   // row=cout, col=pos
                    else
                        acc[m][nf] = __builtin_amdgcn_mfma_f32_16x16x32_bf16(
                            ifr, wfr[nf], acc[m][nf], 0, 0, 0);   // row=pos, col=cout
                }
            }
        }
    }

    const float al = alpha[0];
    __syncthreads();   // everyone done reading inL/wL -> overlay as output tile

    if (OUT_NHWC) {
        // ---- acc -> LDS [16 row][32 x][64 c] bf16 (64 KB), swz on x
        float4 bv[4];
#pragma unroll
        for (int nf = 0; nf < 4; ++nf) bv[nf] = *(const float4*)(bias + nf * 16 + (l4 << 2));
#pragma unroll
        for (int m = 0; m < 2; ++m) {
            int x = m * 16 + l15;
#pragma unroll
            for (int nf = 0; nf < 4; ++nf) {
                f32x4 v = acc[m][nf];
                uint lo = pack2(prelu(v.x + bv[nf].x, al), prelu(v.y + bv[nf].y, al));
                uint hi = pack2(prelu(v.z + bv[nf].z, al), prelu(v.w + bv[nf].w, al));
                int byteoff = ((((wv * 32 + x) * 64) + nf * 16 + (l4 << 2)) * 2) ^ ((x & 7) << 4);
                *(uint2*)(ldsAll + byteoff) = make_uint2(lo, hi);
            }
        }
        __syncthreads();
        // ---- copy-out: 4096 uint4, per row a contiguous 4 KB run
#pragma unroll
        for (int rep = 0; rep < 4; ++rep) {
            int q   = rep * 1024 + t;              // 0..4095
            int x   = (q >> 3) & 31;
            int row = q >> 8;                      // 256 uint4 per row
            int src = (q * 16) ^ ((x & 7) << 4);
            uint4 v = *(const uint4*)(ldsAll + src);
            *(uint4*)(outB + ((size_t)(b * HF + y0 + row) * WF + x0) * 64 +
                      (size_t)(q & 255) * 8) = v;
        }
    } else {
        // ---- acc -> LDS [64 c][16 row][32 x] f32 (128 KB), swz on cout
        float bb[4];
#pragma unroll
        for (int nf = 0; nf < 4; ++nf) bb[nf] = bias[nf * 16 + l15];
#pragma unroll
        for (int m = 0; m < 2; ++m) {
#pragma unroll
            for (int nf = 0; nf < 4; ++nf) {
                f32x4 v = acc[m][nf];
                int cout = nf * 16 + l15;
                float4 st;
                st.x = prelu(v.x + bb[nf], al);
                st.y = prelu(v.y + bb[nf], al);
                st.z = prelu(v.z + bb[nf], al);
                st.w = prelu(v.w + bb[nf], al);
                int byteoff = ((((cout * 16 + wv) * 32) + m * 16 + (l4 << 2)) * 4) ^
                              ((cout & 7) << 4);
                *(float4*)(ldsAll + byteoff) = st;
            }
        }
        __syncthreads();
        // ---- copy-out: 8192 uint4; per (cout,row) a contiguous 128 B run
#pragma unroll
        for (int rep = 0; rep < 8; ++rep) {
            int q    = rep * 1024 + t;             // 0..8191
            int cout = q >> 7;                     // 128 uint4 per cout
            int off  = q & 127;
            int row  = off >> 3;
            int xq   = off & 7;
            int src  = (q * 16) ^ ((cout & 7) << 4);
            float4 v = *(const float4*)(ldsAll + src);
            *(float4*)(outF + (((size_t)b * 64 + cout) << 16) +
                       (size_t)(y0 + row) * WF + x0 + xq * 4) = v;
        }
    }
}

// ---------------------------------------------------------------------------
extern "C" void kernel_launch(void* const* d_in, const int* in_sizes, int n_in,
                              void* d_out, int out_size, void* d_ws, size_t ws_size,
                              hipStream_t stream) {
    const float* x1  = (const float*)d_in[0];
    const float* x2  = (const float*)d_in[1];
    const float* wup = (const float*)d_in[2];
    const float* bup = (const float*)d_in[3];
    const float* w1  = (const float*)d_in[4];
    const float* b1  = (const float*)d_in[5];
    const float* a1  = (const float*)d_in[6];
    const float* w2  = (const float*)d_in[7];
    const float* b2  = (const float*)d_in[8];
    const float* a2  = (const float*)d_in[9];

    char* ws = (char*)d_ws;
    ushort* upB  = (ushort*)ws;                          // 16 MiB (b=2,3 NHWC bf16)
    ushort* hB   = (ushort*)(ws + (size_t)(16 << 20));   // 32 MiB (NHWC bf16)
    ushort* wT1  = (ushort*)(ws + (size_t)(48 << 20));   // 72 KiB
    ushort* wT2  = wT1 + 9 * 64 * 64;                    // 72 KiB
    ushort* wupT = wT2 + 9 * 64 * 64;                    // 64 KiB
    uint4*  zeroBuf = (uint4*)(ws + (size_t)(49 << 20)); // 256 B
    float* out = (float*)d_out;

    k_wprep<<<144, 256, 0, stream>>>(w1, w2, wup, wT1, wT2, wupT, zeroBuf);
    k_upsample_mfma<<<dim3(256, 2), 512, 0, stream>>>(x1, wupT, bup, upB);
    k_conv<0, 1><<<dim3(128, 4), 1024, 0, stream>>>(x2, upB, nullptr, wT1, b1, a1, zeroBuf, hB, nullptr);
    k_conv<1, 0><<<dim3(128, 4), 1024, 0, stream>>>(nullptr, nullptr, hB, wT2, b2, a2, zeroBuf, nullptr, out);
}

// Round 19
// 79.952 us; speedup vs baseline: 1.0474x; 1.0421x over previous
//
#include <hip/hip_runtime.h>

typedef __attribute__((ext_vector_type(8))) short short8;
typedef __attribute__((ext_vector_type(4))) float f32x4;

#define HF 256
#define WF 256

typedef const __attribute__((address_space(1))) void gbl_void;
typedef __attribute__((address_space(3))) void lds_void;

__device__ __forceinline__ ushort f2bf(float f) {
    uint u = __builtin_bit_cast(uint, f);
    u = (u + 0x7FFFu + ((u >> 16) & 1u)) >> 16;
    return (ushort)u;
}
__device__ __forceinline__ uint pack2(float a, float b) {
    return (uint)f2bf(a) | ((uint)f2bf(b) << 16);
}
__device__ __forceinline__ float prelu(float v, float al) { return v >= 0.f ? v : al * v; }

// ---------------------------------------------------------------------------
// Fused weight prep: conv weights w[o][c][3][3] -> wT[tap][o][c] bf16 (x2),
// up weights wup[c][o][p][q] -> wupT[(p*2+q)*64+o][c] bf16, zeroBuf.
// ---------------------------------------------------------------------------
__global__ __launch_bounds__(256) void k_wprep(const float* __restrict__ w1,
                                               const float* __restrict__ w2,
                                               const float* __restrict__ wup,
                                               ushort* __restrict__ wT1,
                                               ushort* __restrict__ wT2,
                                               ushort* __restrict__ wupT,
                                               uint4* __restrict__ zeroBuf) {
    int idx = blockIdx.x * 256 + threadIdx.x;
    if (blockIdx.x == 0 && threadIdx.x < 16)
        zeroBuf[threadIdx.x] = make_uint4(0u, 0u, 0u, 0u);
    if (idx < 36864) {                 // [tap][o][c] : 9*64*64
        int tap = idx >> 12;
        int oc  = idx & 4095;
        int src = oc * 9 + tap;
        wT1[idx] = f2bf(w1[src]);
        wT2[idx] = f2bf(w2[src]);
    }
    if (idx < 32768) {                 // [out][c] : 256*128
        int out = idx >> 7;
        int c   = idx & 127;
        int k   = out >> 6;            // p*2+q
        int o   = out & 63;
        wupT[idx] = f2bf(wup[c * 256 + o * 4 + k]);
    }
}

// ---------------------------------------------------------------------------
// ConvTranspose2d k=2 s=2 for b=2,3 via bf16 MFMA -> upB NHWC [z][y][x][64]
// (unchanged — known good)
// ---------------------------------------------------------------------------
__global__ __launch_bounds__(512) void k_upsample_mfma(const float* __restrict__ x1,
                                                       const ushort* __restrict__ wupT,
                                                       const float* __restrict__ bup,
                                                       ushort* __restrict__ upB) {
    __shared__ __align__(16) char lds[81920];

    const int t   = threadIdx.x;
    const int l   = t & 63;
    const int l15 = l & 15;
    const int l4  = l >> 4;
    const int w   = t >> 6;
    const int pg  = w & 3;
    const int oh  = w >> 2;
    const int i   = blockIdx.x >> 1;
    const int j0  = (blockIdx.x & 1) * 64;
    const int z   = blockIdx.y;
    const int gb  = 2 + z;

    {
        const int j  = t & 63;
        const int cg = t >> 6;
        const size_t base = ((size_t)gb * 128) * 16384 + (size_t)i * 128 + j0 + j;
        float xv[16];
#pragma unroll
        for (int r = 0; r < 2; ++r)
#pragma unroll
            for (int cc = 0; cc < 8; ++cc)
                xv[r * 8 + cc] = x1[base + (size_t)(cg * 16 + r * 8 + cc) * 16384];
#pragma unroll
        for (int r = 0; r < 2; ++r) {
            short8 pk;
#pragma unroll
            for (int cc = 0; cc < 8; ++cc) pk[cc] = (short)f2bf(xv[r * 8 + cc]);
            int ad = (j * 256 + (cg * 16 + r * 8) * 2) ^ ((j & 15) << 4);
            *(short8*)(lds + ad) = pk;
        }
    }
    {
        const uint4* src = (const uint4*)wupT;
#pragma unroll
        for (int rep = 0; rep < 8; ++rep) {
            int q   = rep * 512 + t;
            int out = q >> 4, c16 = q & 15;
            int ad  = 16384 + ((out * 256 + c16 * 16) ^ ((out & 15) << 4));
            *(uint4*)(lds + ad) = src[q];
        }
    }
    float bvv[4];
#pragma unroll
    for (int ob = 0; ob < 4; ++ob) bvv[ob] = bup[ob * 16 + l15];
    __syncthreads();

    f32x4 acc[2][4];
#pragma unroll
    for (int kk = 0; kk < 2; ++kk)
#pragma unroll
        for (int ob = 0; ob < 4; ++ob) acc[kk][ob] = (f32x4){0.f, 0.f, 0.f, 0.f};

#pragma unroll
    for (int ks = 0; ks < 4; ++ks) {
        const int cb = ks * 64 + (l4 << 4);
        const int rowA = pg * 16 + l15;
        short8 xfr = *(const short8*)(lds + ((rowA * 256 + cb) ^ ((rowA & 15) << 4)));
#pragma unroll
        for (int kk = 0; kk < 2; ++kk)
#pragma unroll
            for (int ob = 0; ob < 4; ++ob) {
                int out = (oh * 2 + kk) * 64 + ob * 16 + l15;
                short8 wfr = *(const short8*)(lds + 16384 +
                              ((out * 256 + cb) ^ ((out & 15) << 4)));
                acc[kk][ob] = __builtin_amdgcn_mfma_f32_16x16x32_bf16(xfr, wfr, acc[kk][ob], 0, 0, 0);
            }
    }
    __syncthreads();

    ushort* OUT = (ushort*)lds;
#pragma unroll
    for (int kk = 0; kk < 2; ++kk) {
        const int k = oh * 2 + kk, p = k >> 1, q = k & 1;
#pragma unroll
        for (int ob = 0; ob < 4; ++ob) {
            const int o = ob * 16 + l15;
#pragma unroll
            for (int r = 0; r < 4; ++r) {
                int jl = pg * 16 + l4 * 4 + r;
                int x  = 2 * jl + q;
                OUT[(p * 128 + x) * 64 + o] = f2bf(acc[kk][ob][r] + bvv[ob]);
            }
        }
    }
    __syncthreads();

#pragma unroll
    for (int rep = 0; rep < 4; ++rep) {
        int idx = rep * 512 + t;
        int p   = idx >> 10;
        int y   = 2 * i + p;
        uint4 v = *(const uint4*)(lds + idx * 16);
        size_t g = (size_t)(z * HF + y) * 2048 + (size_t)j0 * 16 + (idx & 1023);
        ((uint4*)upB)[g] = v;
    }
}

// ---------------------------------------------------------------------------
// k_conv (champion, R11): 1024 thr / 16 waves (4 waves/SIMD), tile 32x16,
// all weights + input staged in LDS via async global_load_lds (pre-swizzled
// source, linear dest), ONE barrier, then a pure ds_read+MFMA K-loop
// (unroll-1 taps). Wave = 1 y-row x 32 x x 64 couts, acc[2][4] = 32 VGPR.
// Measured best: 80.2 us total, convs ~41 us profiled, 0 bank conflicts.
// ---------------------------------------------------------------------------
template<int IN_MODE, int OUT_NHWC>
__global__ __launch_bounds__(1024, 1) void k_conv(const float* __restrict__ x2,
                                                  const ushort* __restrict__ upB,
                                                  const ushort* __restrict__ inB,
                                                  const ushort* __restrict__ wT,
                                                  const float* __restrict__ bias,
                                                  const float* __restrict__ alpha,
                                                  const uint4* __restrict__ zeroBuf,
                                                  ushort* __restrict__ outB,
                                                  float* __restrict__ outF) {
    __shared__ __align__(16) ushort inL[5120 * 8];       // 80 KB (4896 used + pad)
    __shared__ __align__(16) ushort wL[9 * 64 * 64];     // 72 KB [tap][o][c], swz on o

    const int t   = threadIdx.x;
    const int wv  = t >> 6;          // wave id -> output row (0..15)
    const int l   = t & 63;
    const int l15 = l & 15;
    const int l4  = l >> 4;
    const int x0  = (blockIdx.x & 7) * 32;
    const int y0  = (blockIdx.x >> 3) * 16;
    const int b   = blockIdx.y;

    // ---- stage ALL weights: linear dest, pre-swizzled source (4608 uint4)
    {
        const char* wTb = (const char*)wT;
#pragma unroll
        for (int rep = 0; rep < 4; ++rep) {
            int d   = rep * 1024 + t;
            int tap = d >> 9;
            int dp  = d & 511;
            int s   = (tap << 9) + (dp ^ ((dp >> 3) & 7));
            __builtin_amdgcn_global_load_lds(
                (gbl_void*)(wTb + (size_t)s * 16),
                (lds_void*)((char*)wL + (size_t)((rep << 10) + (wv << 6)) * 16),
                16, 0, 0);
        }
        if (wv < 8) {                              // wave-uniform tail: 4096..4607
            int d   = 4096 + (wv << 6) + l;
            int tap = d >> 9;
            int dp  = d & 511;
            int s   = (tap << 9) + (dp ^ ((dp >> 3) & 7));
            __builtin_amdgcn_global_load_lds(
                (gbl_void*)(wTb + (size_t)s * 16),
                (lds_void*)((char*)wL + (size_t)(4096 + (wv << 6)) * 16),
                16, 0, 0);
        }
    }

    // ---- stage input tile (18 x 34 x 64ch = 4896 uint4, padded to 5120)
    if (IN_MODE == 1 || b >= 2) {
        const ushort* src0 = (IN_MODE == 1) ? inB : upB;
        const int bb = (IN_MODE == 1) ? b : (b - 2);
#pragma unroll
        for (int rep = 0; rep < 5; ++rep) {
            int d  = rep * 1024 + t;                 // 0..5119
            int r  = d / 272;
            int wi = d - r * 272;
            int wq = wi ^ ((wi >> 3) & 7);           // pre-swizzled source element
            int x  = wq >> 3, c8 = wq & 7;
            int gy = y0 - 1 + r;
            int gx = x0 - 1 + x;
            const void* g;
            if (d < 4896 && (unsigned)gy < HF && (unsigned)gx < WF) {
                size_t pos = (size_t)(bb * HF + gy) * WF + gx;
                g = (const void*)(src0 + pos * 64 + c8 * 8);
            } else {
                g = (const void*)zeroBuf;
            }
            __builtin_amdgcn_global_load_lds(
                (gbl_void*)g,
                (lds_void*)((char*)inL + (size_t)((rep << 10) + (wv << 6)) * 16),
                16, 0, 0);
        }
    } else {
        // manual path: x2 f32 NHWC -> bf16, swizzled ds_write
        for (int q = t; q < 18 * 34 * 8; q += 1024) {
            int r   = q / 272;
            int rem = q - r * 272;
            int x   = rem >> 3;
            int c8  = rem & 7;
            int gy = y0 - 1 + r;
            int gx = x0 - 1 + x;
            uint4 v = make_uint4(0u, 0u, 0u, 0u);
            if ((unsigned)gy < HF && (unsigned)gx < WF) {
                size_t pos = (size_t)(b * HF + gy) * WF + gx;
                const float4* s = (const float4*)(x2 + pos * 64 + c8 * 8);
                float4 u0 = s[0], u1 = s[1];
                v = make_uint4(pack2(u0.x, u0.y), pack2(u0.z, u0.w),
                               pack2(u1.x, u1.y), pack2(u1.z, u1.w));
            }
            int ad = (q * 16) ^ ((x & 7) << 4);
            *(uint4*)((char*)inL + ad) = v;
        }
    }
    __syncthreads();

    f32x4 acc[2][4];   // [m][nf]
#pragma unroll
    for (int m = 0; m < 2; ++m)
#pragma unroll
        for (int nf = 0; nf < 4; ++nf) acc[m][nf] = (f32x4){0.f, 0.f, 0.f, 0.f};

    // ---- K-loop: 9 taps, pure LDS + MFMA, zero barriers
#pragma unroll 1
    for (int tap = 0; tap < 9; ++tap) {
        const int ky = tap / 3;
        const int kx = tap - ky * 3;
        const char* wPage = (const char*)wL + tap * 8192;
#pragma unroll
        for (int ks = 0; ks < 2; ++ks) {
            short8 wfr[4];
#pragma unroll
            for (int nf = 0; nf < 4; ++nf) {
                int o = nf * 16 + l15;
                int ad = (o * 128 + ks * 64 + (l4 << 4)) ^ ((o & 7) << 4);
                wfr[nf] = *(const short8*)(wPage + ad);
            }
#pragma unroll
            for (int m = 0; m < 2; ++m) {
                int ry = wv + ky;
                int xl = m * 16 + l15 + kx;
                int ad = ((ry * 34 + xl) * 128 + ks * 64 + (l4 << 4)) ^ ((xl & 7) << 4);
                short8 ifr = *(const short8*)((const char*)inL + ad);
#pragma unroll
                for (int nf = 0; nf < 4; ++nf) {
                    if (OUT_NHWC)
                        acc[m][nf] = __builtin_amdgcn_mfma_f32_16x16x32_bf16(
                            wfr[nf], ifr, acc[m][nf], 0, 0, 0);   // row=cout, col=pos
                    else
                        acc[m][nf] = __builtin_amdgcn_mfma_f32_16x16x32_bf16(
                            ifr, wfr[nf], acc[m][nf], 0, 0, 0);   // row=pos, col=cout
                }
            }
        }
    }

    const float al = alpha[0];
    const int y = y0 + wv;
    if (OUT_NHWC) {
        float4 bv[4];
#pragma unroll
        for (int nf = 0; nf < 4; ++nf) bv[nf] = *(const float4*)(bias + nf * 16 + (l4 << 2));
#pragma unroll
        for (int m = 0; m < 2; ++m) {
            int x = x0 + m * 16 + l15;
#pragma unroll
            for (int nf = 0; nf < 4; ++nf) {
                f32x4 v = acc[m][nf];
                uint lo = pack2(prelu(v.x + bv[nf].x, al), prelu(v.y + bv[nf].y, al));
                uint hi = pack2(prelu(v.z + bv[nf].z, al), prelu(v.w + bv[nf].w, al));
                int cb = nf * 16 + (l4 << 2);
                *(uint2*)(outB + ((size_t)(b * HF + y) * WF + x) * 64 + cb) = make_uint2(lo, hi);
            }
        }
    } else {
        float bb[4];
#pragma unroll
        for (int nf = 0; nf < 4; ++nf) bb[nf] = bias[nf * 16 + l15];
#pragma unroll
        for (int m = 0; m < 2; ++m) {
            int xb = x0 + m * 16 + (l4 << 2);
#pragma unroll
            for (int nf = 0; nf < 4; ++nf) {
                f32x4 v = acc[m][nf];
                int cout = nf * 16 + l15;
                float4 st;
                st.x = prelu(v.x + bb[nf], al);
                st.y = prelu(v.y + bb[nf], al);
                st.z = prelu(v.z + bb[nf], al);
                st.w = prelu(v.w + bb[nf], al);
                *(float4*)(outF + (((size_t)b * 64 + cout) << 16) + y * WF + xb) = st;
            }
        }
    }
}

// ---------------------------------------------------------------------------
extern "C" void kernel_launch(void* const* d_in, const int* in_sizes, int n_in,
                              void* d_out, int out_size, void* d_ws, size_t ws_size,
                              hipStream_t stream) {
    const float* x1  = (const float*)d_in[0];
    const float* x2  = (const float*)d_in[1];
    const float* wup = (const float*)d_in[2];
    const float* bup = (const float*)d_in[3];
    const float* w1  = (const float*)d_in[4];
    const float* b1  = (const float*)d_in[5];
    const float* a1  = (const float*)d_in[6];
    const float* w2  = (const float*)d_in[7];
    const float* b2  = (const float*)d_in[8];
    const float* a2  = (const float*)d_in[9];

    char* ws = (char*)d_ws;
    ushort* upB  = (ushort*)ws;                          // 16 MiB (b=2,3 NHWC bf16)
    ushort* hB   = (ushort*)(ws + (size_t)(16 << 20));   // 32 MiB (NHWC bf16)
    ushort* wT1  = (ushort*)(ws + (size_t)(48 << 20));   // 72 KiB
    ushort* wT2  = wT1 + 9 * 64 * 64;                    // 72 KiB
    ushort* wupT = wT2 + 9 * 64 * 64;                    // 64 KiB
    uint4*  zeroBuf = (uint4*)(ws + (size_t)(49 << 20)); // 256 B, zeroed by k_wprep
    float* out = (float*)d_out;

    k_wprep<<<144, 256, 0, stream>>>(w1, w2, wup, wT1, wT2, wupT, zeroBuf);
    k_upsample_mfma<<<dim3(256, 2), 512, 0, stream>>>(x1, wupT, bup, upB);
    k_conv<0, 1><<<dim3(128, 4), 1024, 0, stream>>>(x2, upB, nullptr, wT1, b1, a1, zeroBuf, hB, nullptr);
    k_conv<1, 0><<<dim3(128, 4), 1024, 0, stream>>>(nullptr, nullptr, hB, wT2, b2, a2, zeroBuf, nullptr, out);
}